// Round 8
// baseline (654.030 us; speedup 1.0000x reference)
//
#include <hip/hip_runtime.h>
#include <math.h>

#define DIM    64
#define HID    128
#define KNN    16
#define CHUNK  512     // candidates staged per block iteration
#define LCAP   64      // per-query survivor list capacity
#define LSTR   65      // list stride (u64), bank-conflict-free for owners
#define EPS2   0.01f   // 2*eps filter band (eps ~0.004 worst-case)

typedef unsigned long long u64;
typedef __attribute__((ext_vector_type(8))) short short8;   // 8 bf16
typedef __attribute__((ext_vector_type(4))) float f32x4;    // MFMA C/D

// ---------------- bf16 helpers ----------------
__device__ __forceinline__ unsigned short bf16_rn(float f) {
    unsigned u = __float_as_uint(f);
    unsigned r = u + 0x7FFFu + ((u >> 16) & 1u);   // RN-even
    return (unsigned short)(r >> 16);
}
__device__ __forceinline__ float bf16_f32(unsigned short b) {
    return __uint_as_float(((unsigned)b) << 16);
}

// monotonic (dist,idx) -> u64 key (handles negative d2); smaller = lex-better
__device__ __forceinline__ u64 pack_key(float d, unsigned idx) {
    unsigned u = __float_as_uint(d);
    unsigned m = u ^ ((unsigned)(((int)u) >> 31) | 0x80000000u);
    return ((u64)m << 32) | idx;
}

// value-only 16-min network (approx-distance compaction)
__device__ __forceinline__ void ins16f(float (&b)[16], float d) {
    float c = d;
    #pragma unroll
    for (int i = 0; i < 16; ++i) {
        float lo = fminf(c, b[i]);
        float hi = fmaxf(c, b[i]);
        b[i] = lo; c = hi;
    }
}

// u64-key sorted insert (exact final selection)
__device__ __forceinline__ void ins16k(u64 (&b)[16], u64 key) {
    u64 c = key;
    #pragma unroll
    for (int i = 0; i < 16; ++i) {
        bool lt = c < b[i];
        u64 lo = lt ? c : b[i];
        u64 hi = lt ? b[i] : c;
        b[i] = lo; c = hi;
    }
}

// exact per-query selection from survivor list (numpy-order fp32, lex ties)
__device__ void exact_select(const float* __restrict__ pos, int bbase, int qloc,
                             const u64* __restrict__ L, int n,
                             int* __restrict__ out_idx, int qi) {
    #pragma clang fp contract(off)
    const float* pq = pos + (size_t)(bbase + qloc) * 3;
    float qx = pq[0], qy = pq[1], qz = pq[2];
    float qs = (qx * qx + qy * qy) + qz * qz;
    u64 b[16];
    #pragma unroll
    for (int k = 0; k < 16; ++k) b[k] = 0xFFFFFFFFFFFFFFFFull;
    for (int i = 0; i < n; ++i) {
        unsigned c = (unsigned)(L[i] & 0xFFFFFFFFull);
        const float* pc = pos + (size_t)(bbase + (int)c) * 3;
        float ax = pc[0], ay = pc[1], az = pc[2];
        float dot = (qx * ax + qy * ay) + qz * az;
        float as_ = (ax * ax + ay * ay) + az * az;
        float d2  = (qs + as_) - 2.0f * dot;
        u64 key = pack_key(d2, c);
        if (key < b[15]) ins16k(b, key);
    }
    #pragma unroll
    for (int k = 0; k < 16; ++k)
        out_idx[k * 64 + qi] = (int)(b[k] & 0xFFFFFFFFull);
}

// Kernel 1: MFMA-filtered exact 16-NN + gather + aggregate.
// Wave owns 16 queries x all 4096 candidates (lists wave-private).
__global__ __launch_bounds__(256, 3) void knn_mfma(
    const float* __restrict__ x, const float* __restrict__ pos,
    float* __restrict__ agg_out)
{
    // 50.2 KB LDS: bpack hi/lo (16 KB) + lists (33.3 KB) + cnt/thr/zero.
    // Final phase aliases bpack region as mi2[16][64].
    __shared__ u64 smem[6274];
    unsigned short* bh = (unsigned short*)smem;       // [CHUNK*8]
    unsigned short* bl = bh + CHUNK * 8;
    u64*   lists = smem + 2048;                        // [64*LSTR]
    unsigned* cntA = (unsigned*)(smem + 6208);         // [64]
    float* thrF = (float*)(smem + 6240);               // [64]
    unsigned short* zeroPack = (unsigned short*)(smem + 6272);  // 16 B zeros

    const int tid  = threadIdx.x;
    const int w    = tid >> 6;
    const int lane = tid & 63;
    const int quad = lane >> 4;
    const int col  = lane & 15;

    const int qb    = blockIdx.x;            // 1024 blocks x 64 queries
    const int bbase = (qb >> 6) << 12;
    const int qrow0 = (qb & 63) << 6;        // block's first query (batch-local)

    if (tid < 64) { cntA[tid] = 0u; thrF[tid] = INFINITY; }
    if (tid < 8)  zeroPack[tid] = 0;

    // A-fragments: query packets {qx,qy,qz,qs,1,0,0,0}, hi/lo split.
    // A[m=lane&15][k=quad*8+j]: quad 0 holds the packet, quads 1-3 zeros.
    short8 ah = (short8)0, al = (short8)0;
    if (quad == 0) {
        const float* pq = pos + (size_t)(bbase + qrow0 + w * 16 + col) * 3;
        float qx = pq[0], qy = pq[1], qz = pq[2];
        float qs = (qx * qx + qy * qy) + qz * qz;
        float v[8] = {qx, qy, qz, qs, 1.0f, 0.f, 0.f, 0.f};
        #pragma unroll
        for (int j = 0; j < 8; ++j) {
            unsigned short hb = bf16_rn(v[j]);
            ah[j] = (short)hb;
            al[j] = (short)bf16_rn(v[j] - bf16_f32(hb));
        }
    }

    float t0 = INFINITY, t1 = INFINITY, t2 = INFINITY, t3 = INFINITY;

    for (int chunk = 0; chunk < 8; ++chunk) {
        __syncthreads();                     // init/previous chunk consumed
        // stage candidate packets {-2cx,-2cy,-2cz,1,cs,0,0,0} hi/lo
        for (int e = tid; e < CHUNK; e += 256) {
            const float* pc = pos + (size_t)(bbase + (chunk << 9) + e) * 3;
            float cx = pc[0], cy = pc[1], cz = pc[2];
            float cs = (cx * cx + cy * cy) + cz * cz;
            float v[8] = {-2.f * cx, -2.f * cy, -2.f * cz, 1.0f, cs, 0.f, 0.f, 0.f};
            short8 hi, lo;
            #pragma unroll
            for (int j = 0; j < 8; ++j) {
                unsigned short hb = bf16_rn(v[j]);
                hi[j] = (short)hb;
                lo[j] = (short)bf16_rn(v[j] - bf16_f32(hb));
            }
            *(short8*)(bh + e * 8) = hi;
            *(short8*)(bl + e * 8) = lo;
        }
        __syncthreads();

        for (int t = 0; t < 32; ++t) {
            // B-frags: quad 0 reads candidate packet, quads 1-3 read zeros
            const int coff = ((t << 4) + col) << 3;
            const unsigned short* ph = (quad == 0) ? (bh + coff) : zeroPack;
            const unsigned short* pl = (quad == 0) ? (bl + coff) : zeroPack;
            short8 vbh = *(const short8*)ph;
            short8 vbl = *(const short8*)pl;

            f32x4 acc = (f32x4){0.f, 0.f, 0.f, 0.f};
            acc = __builtin_amdgcn_mfma_f32_16x16x32_bf16(ah, vbh, acc, 0, 0, 0);
            acc = __builtin_amdgcn_mfma_f32_16x16x32_bf16(al, vbh, acc, 0, 0, 0);
            acc = __builtin_amdgcn_mfma_f32_16x16x32_bf16(ah, vbl, acc, 0, 0, 0);
            // acc[r] = d~2(query quad*4+r, candidate col)

            bool p = (acc[0] <= t0) | (acc[1] <= t1) | (acc[2] <= t2) | (acc[3] <= t3);
            if (__ballot(p) != 0ull) {
                const int cl = (chunk << 9) + (t << 4) + col;   // batch-local cand
                const int qbase = (w << 4) + (quad << 2);
                if (acc[0] <= t0) {
                    int qi = qbase + 0;
                    if (cl != qrow0 + qi) {
                        unsigned pp = atomicAdd(&cntA[qi], 1u);
                        if (pp < (unsigned)LCAP)
                            lists[qi * LSTR + pp] =
                                ((u64)__float_as_uint(acc[0]) << 32) | (unsigned)cl;
                    }
                }
                if (acc[1] <= t1) {
                    int qi = qbase + 1;
                    if (cl != qrow0 + qi) {
                        unsigned pp = atomicAdd(&cntA[qi], 1u);
                        if (pp < (unsigned)LCAP)
                            lists[qi * LSTR + pp] =
                                ((u64)__float_as_uint(acc[1]) << 32) | (unsigned)cl;
                    }
                }
                if (acc[2] <= t2) {
                    int qi = qbase + 2;
                    if (cl != qrow0 + qi) {
                        unsigned pp = atomicAdd(&cntA[qi], 1u);
                        if (pp < (unsigned)LCAP)
                            lists[qi * LSTR + pp] =
                                ((u64)__float_as_uint(acc[2]) << 32) | (unsigned)cl;
                    }
                }
                if (acc[3] <= t3) {
                    int qi = qbase + 3;
                    if (cl != qrow0 + qi) {
                        unsigned pp = atomicAdd(&cntA[qi], 1u);
                        if (pp < (unsigned)LCAP)
                            lists[qi * LSTR + pp] =
                                ((u64)__float_as_uint(acc[3]) << 32) | (unsigned)cl;
                    }
                }
            }

            // compaction trigger: 16-headroom guarantees no list overflow
            unsigned cother = cntA[(w << 4) + col];   // broadcast within quad
            bool trig  = (lane < 16) && (cother >= (unsigned)(LCAP - 16));
            bool force = (chunk == 0) && (t == 1);    // bootstrap: first 32 appended
            if (force || (__ballot(trig) != 0ull)) {
                if (lane < 16) {
                    int qi = (w << 4) + lane;
                    int n = (int)min(cntA[qi], (unsigned)LCAP);
                    float b16[16];
                    #pragma unroll
                    for (int k = 0; k < 16; ++k) b16[k] = INFINITY;
                    u64* L = lists + qi * LSTR;
                    for (int i = 0; i < n; ++i) {
                        float d = __uint_as_float((unsigned)(L[i] >> 32));
                        if (d < b16[15]) ins16f(b16, d);
                    }
                    float keep = b16[15] + EPS2;   // d~16 + 2eps (INF-safe)
                    int m2 = 0;
                    for (int i = 0; i < n; ++i) {
                        u64 e = L[i];
                        if (__uint_as_float((unsigned)(e >> 32)) <= keep) {
                            L[m2] = e; ++m2;
                        }
                    }
                    cntA[qi] = (unsigned)m2;
                    thrF[qi] = keep;
                }
                const int qb4 = (w << 4) + (quad << 2);
                t0 = thrF[qb4 + 0]; t1 = thrF[qb4 + 1];
                t2 = thrF[qb4 + 2]; t3 = thrF[qb4 + 3];
            }
        }
    }

    __syncthreads();                  // scan done; bpack region reusable

    // exact final selection (owner lane per query), write mi2 into bpack region
    int* mi2 = (int*)smem;            // [16][64]
    if (lane < 16) {
        int qi = (w << 4) + lane;
        int n = (int)min(cntA[qi], (unsigned)LCAP);
        exact_select(pos, bbase, qrow0 + qi, lists + qi * LSTR, n, mi2, qi);
    }
    __syncthreads();

    // gather + aggregate: 4 threads/row, 16 cols each. h = x + sum(nb).
    {
        const int r  = tid >> 2;
        const int p  = tid & 3;
        const int q  = (qb << 6) + r;
        const int cb = p << 4;

        int idxs[KNN];
        #pragma unroll
        for (int k = 0; k < KNN; ++k) idxs[k] = mi2[k * 64 + r];

        float4 a0 = *(const float4*)(x + (size_t)q * DIM + cb + 0);
        float4 a1 = *(const float4*)(x + (size_t)q * DIM + cb + 4);
        float4 a2 = *(const float4*)(x + (size_t)q * DIM + cb + 8);
        float4 a3 = *(const float4*)(x + (size_t)q * DIM + cb + 12);

        #pragma unroll 4
        for (int k = 0; k < KNN; ++k) {
            const float* nr = x + (size_t)(bbase + idxs[k]) * DIM + cb;
            float4 v0 = *(const float4*)(nr + 0);
            float4 v1 = *(const float4*)(nr + 4);
            float4 v2 = *(const float4*)(nr + 8);
            float4 v3 = *(const float4*)(nr + 12);
            a0.x += v0.x; a0.y += v0.y; a0.z += v0.z; a0.w += v0.w;
            a1.x += v1.x; a1.y += v1.y; a1.z += v1.z; a1.w += v1.w;
            a2.x += v2.x; a2.y += v2.y; a2.z += v2.z; a2.w += v2.w;
            a3.x += v3.x; a3.y += v3.y; a3.z += v3.z; a3.w += v3.w;
        }

        float* o = agg_out + (size_t)q * DIM + cb;
        *(float4*)(o + 0)  = a0;
        *(float4*)(o + 4)  = a1;
        *(float4*)(o + 8)  = a2;
        *(float4*)(o + 12) = a3;
    }
}

// ============ MFMA MLP path (unchanged from R7, validated) ============
__global__ void prep_bf16(const float* __restrict__ W1,
                          const float* __restrict__ W2,
                          unsigned short* __restrict__ ws) {
    int e = blockIdx.x * 256 + threadIdx.x;   // 16384 threads
    if (e < 8192) {
        int n = e >> 6, k = e & 63;
        float v = W1[k * HID + n];
        unsigned short h = bf16_rn(v);
        ws[e] = h;
        ws[8192 + e] = bf16_rn(v - bf16_f32(h));
    } else {
        int f = e - 8192;
        int n = f >> 7, k = f & 127;
        float v = W2[k * DIM + n];
        unsigned short h = bf16_rn(v);
        ws[16384 + f] = h;
        ws[24576 + f] = bf16_rn(v - bf16_f32(h));
    }
}

__global__ __launch_bounds__(256, 2) void mlp_mfma(
    const unsigned short* __restrict__ ws,
    const float* __restrict__ b1, const float* __restrict__ b2,
    float* __restrict__ io)
{
    __shared__ unsigned short hh[64 * 136];
    __shared__ unsigned short hl[64 * 136];

    const int tid  = threadIdx.x;
    const int w    = tid >> 6;
    const int lane = tid & 63;
    const int quad = lane >> 4;
    const int col  = lane & 15;
    const int rowbase = blockIdx.x * 64 + w * 16;

    const unsigned short* w1h = ws;
    const unsigned short* w1l = ws + 8192;
    const unsigned short* w2h = ws + 16384;
    const unsigned short* w2l = ws + 24576;

    short8 ah[2], al[2];
    #pragma unroll
    for (int ks = 0; ks < 2; ++ks) {
        const float* xr = io + (size_t)(rowbase + col) * DIM + ks * 32 + quad * 8;
        float4 v0 = *(const float4*)(xr);
        float4 v1 = *(const float4*)(xr + 4);
        float xv[8] = {v0.x, v0.y, v0.z, v0.w, v1.x, v1.y, v1.z, v1.w};
        #pragma unroll
        for (int j = 0; j < 8; ++j) {
            unsigned short hb = bf16_rn(xv[j]);
            ah[ks][j] = (short)hb;
            al[ks][j] = (short)bf16_rn(xv[j] - bf16_f32(hb));
        }
    }

    f32x4 acc1[8];
    #pragma unroll
    for (int t = 0; t < 8; ++t) acc1[t] = (f32x4){0.f, 0.f, 0.f, 0.f};

    #pragma unroll
    for (int t = 0; t < 8; ++t) {
        #pragma unroll
        for (int ks = 0; ks < 2; ++ks) {
            const int off = (t * 16 + col) * 64 + ks * 32 + quad * 8;
            short8 bh = *(const short8*)(w1h + off);
            short8 bl = *(const short8*)(w1l + off);
            acc1[t] = __builtin_amdgcn_mfma_f32_16x16x32_bf16(ah[ks], bh, acc1[t], 0, 0, 0);
            acc1[t] = __builtin_amdgcn_mfma_f32_16x16x32_bf16(al[ks], bh, acc1[t], 0, 0, 0);
            acc1[t] = __builtin_amdgcn_mfma_f32_16x16x32_bf16(ah[ks], bl, acc1[t], 0, 0, 0);
        }
    }

    #pragma unroll
    for (int t = 0; t < 8; ++t) {
        float bv = b1[t * 16 + col];
        #pragma unroll
        for (int r = 0; r < 4; ++r) {
            float h = fmaxf(acc1[t][r] + bv, 0.0f);
            unsigned short hb = bf16_rn(h);
            unsigned short lb = bf16_rn(h - bf16_f32(hb));
            int rowL = w * 16 + quad * 4 + r;
            hh[rowL * 136 + t * 16 + col] = hb;
            hl[rowL * 136 + t * 16 + col] = lb;
        }
    }
    __syncthreads();

    short8 a2h[4], a2l[4];
    #pragma unroll
    for (int ks = 0; ks < 4; ++ks) {
        const int off = (w * 16 + col) * 136 + ks * 32 + quad * 8;
        a2h[ks] = *(const short8*)(hh + off);
        a2l[ks] = *(const short8*)(hl + off);
    }

    f32x4 acc2[4];
    #pragma unroll
    for (int t = 0; t < 4; ++t) acc2[t] = (f32x4){0.f, 0.f, 0.f, 0.f};

    #pragma unroll
    for (int t = 0; t < 4; ++t) {
        #pragma unroll
        for (int ks = 0; ks < 4; ++ks) {
            const int off = (t * 16 + col) * 128 + ks * 32 + quad * 8;
            short8 bh = *(const short8*)(w2h + off);
            short8 bl = *(const short8*)(w2l + off);
            acc2[t] = __builtin_amdgcn_mfma_f32_16x16x32_bf16(a2h[ks], bh, acc2[t], 0, 0, 0);
            acc2[t] = __builtin_amdgcn_mfma_f32_16x16x32_bf16(a2l[ks], bh, acc2[t], 0, 0, 0);
            acc2[t] = __builtin_amdgcn_mfma_f32_16x16x32_bf16(a2h[ks], bl, acc2[t], 0, 0, 0);
        }
    }

    #pragma unroll
    for (int t = 0; t < 4; ++t) {
        float bv = b2[t * 16 + col];
        #pragma unroll
        for (int r = 0; r < 4; ++r) {
            io[(size_t)(rowbase + quad * 4 + r) * DIM + t * 16 + col] =
                acc2[t][r] + bv;
        }
    }
}

extern "C" void kernel_launch(void* const* d_in, const int* in_sizes, int n_in,
                              void* d_out, int out_size, void* d_ws, size_t ws_size,
                              hipStream_t stream) {
    (void)in_sizes; (void)n_in; (void)out_size; (void)ws_size;
    const float* x   = (const float*)d_in[0];
    const float* pos = (const float*)d_in[1];
    // d_in[2] = batch indices: deterministic (i // (N/B)), not needed
    const float* W1  = (const float*)d_in[3];
    const float* b1  = (const float*)d_in[4];
    const float* W2  = (const float*)d_in[5];
    const float* b2  = (const float*)d_in[6];
    float* out = (float*)d_out;

    prep_bf16<<<dim3(64), dim3(256), 0, stream>>>(W1, W2, (unsigned short*)d_ws);
    knn_mfma<<<dim3(1024), dim3(256), 0, stream>>>(x, pos, out);
    mlp_mfma<<<dim3(1024), dim3(256), 0, stream>>>(
        (const unsigned short*)d_ws, b1, b2, out);
}